// Round 13
// baseline (1932.665 us; speedup 1.0000x reference)
//
#include <hip/hip_runtime.h>
#include <math.h>
#include <stdint.h>

#define NPOS  32768
#define LOG2N 15
#define BATCH 8
#define TOTAL (BATCH * NPOS)          // 262144 positions
#define HE    ((size_t)16 * TOTAL)    // one fp32 h buffer, elements (16 MiB)
#define HBFE  ((size_t)16 * TOTAL)    // one bf16 H buffer, elements (8 MiB)
#define PPB   512                     // positions per block (pair kernel)

typedef __attribute__((ext_vector_type(8))) short short8v;  // 8 bf16 = 4 VGPR
typedef __attribute__((ext_vector_type(4))) float f32x4;    // MFMA C/D

__device__ __forceinline__ float fast_tanh(float x) {
    float t = __expf(-2.f * x);
    return fmaf(2.f, __builtin_amdgcn_rcpf(1.f + t), -1.f);
}
__device__ __forceinline__ float fast_sigmoid(float x) {
    return __builtin_amdgcn_rcpf(1.f + __expf(-x));
}
__device__ __forceinline__ unsigned short bf16rne(float x) {
    unsigned u = __float_as_uint(x);
    u = (u + 0x7fffu + ((u >> 16) & 1u)) >> 16;
    return (unsigned short)u;
}

__device__ __forceinline__ void store_bf_row(unsigned short* __restrict__ bf,
                                             int t, const float* w)
{
    unsigned pk[8];
#pragma unroll
    for (int q = 0; q < 8; ++q)
        pk[q] = (unsigned)bf16rne(w[2 * q]) | ((unsigned)bf16rne(w[2 * q + 1]) << 16);
    uint4* ob = (uint4*)(bf + (size_t)t * 16);
    ob[0] = make_uint4(pk[0], pk[1], pk[2], pk[3]);
    ob[1] = make_uint4(pk[4], pk[5], pk[6], pk[7]);
}

__device__ __forceinline__ void store_rows(float* __restrict__ fp,
                                           unsigned short* __restrict__ bf,
                                           int t, const float* w)
{
    float4* o = (float4*)(fp + (size_t)t * 16);
#pragma unroll
    for (int q = 0; q < 4; ++q)
        o[q] = make_float4(w[4 * q], w[4 * q + 1], w[4 * q + 2], w[4 * q + 3]);
    store_bf_row(bf, t, w);
}

// ---- gated conv core: out[c] = res[c] + tanh(f)·sigmoid(g) ----------------
__device__ __forceinline__ void gated(const float* __restrict__ wf,
                                      const float* __restrict__ bfv,
                                      const float* __restrict__ wg,
                                      const float* __restrict__ bgv,
                                      const float* ra, const float* pa,
                                      float* wa)
{
#pragma unroll
    for (int c = 0; c < 16; ++c) {
        float fa = bfv[c], ga = bgv[c];
#pragma unroll
        for (int ic = 0; ic < 16; ++ic) {
            fa = fmaf(wf[(c * 16 + ic) * 2 + 0], pa[ic], fa);
            fa = fmaf(wf[(c * 16 + ic) * 2 + 1], ra[ic], fa);
            ga = fmaf(wg[(c * 16 + ic) * 2 + 0], pa[ic], ga);
            ga = fmaf(wg[(c * 16 + ic) * 2 + 1], ra[ic], ga);
        }
        wa[c] = fmaf(fast_tanh(fa), fast_sigmoid(ga), ra[c]);
    }
}

// ================= init: h_0 (fp32 row-major) + Hbf_0 ======================
__global__ __launch_bounds__(256) void init_kernel_rm1(
    const int* __restrict__ x_int, const float* __restrict__ W0,
    const float* __restrict__ b0,
    float* __restrict__ hfp, unsigned short* __restrict__ hbf)
{
    int t = blockIdx.x * 256 + threadIdx.x;
    int n = t & (NPOS - 1);
    const float sc = 1.f / 32768.f;
    float xs  = (n >= 1) ? (float)x_int[t - 1] * sc : 0.f;
    float xsp = (n >= 2) ? (float)x_int[t - 2] * sc : 0.f;
    float w[16];
#pragma unroll
    for (int c = 0; c < 16; ++c)
        w[c] = xs + W0[c * 2 + 0] * xsp + W0[c * 2 + 1] * xs + b0[c];
    store_rows(hfp, hbf, t, w);
}

// ================= fused layer pair (2p, 2p+1) =============================
// Block covers positions [base, base+512). Phase 1: layer A on
// [base-dB, base+512) -> LDS hmid[16][769] (col-major, conflict-free) and
// Hbf_A for valid range. Phase 2: layer B from LDS -> hOut fp32 + Hbf_B.
__global__ __launch_bounds__(256, 4) void pair_kernel(
    const float* __restrict__ hIn, float* __restrict__ hOut,
    unsigned short* __restrict__ HbfA, unsigned short* __restrict__ HbfB,
    const float* __restrict__ wfA, const float* __restrict__ bfA,
    const float* __restrict__ wgA, const float* __restrict__ bgA,
    const float* __restrict__ wfB, const float* __restrict__ bfB,
    const float* __restrict__ wgB, const float* __restrict__ bgB,
    int dA, int dB)
{
    __shared__ float hmid[16][PPB + 256 + 1];   // col-major: [ch][loc]

    int base = blockIdx.x * PPB;
    int span = PPB + dB;                        // phase-1 position count

    // ---- phase 1: layer A over [base-dB, base+PPB)
#pragma unroll 1
    for (int loc = threadIdx.x; loc < span; loc += 256) {
        int t  = base - dB + loc;
        int tc = (t < 0) ? 0 : t;
        int n  = t & (NPOS - 1);

        float ra[16], pa[16];
        {
            const float4* p = (const float4*)(hIn + (size_t)tc * 16);
#pragma unroll
            for (int q = 0; q < 4; ++q) {
                float4 v = p[q];
                ra[4 * q] = v.x; ra[4 * q + 1] = v.y;
                ra[4 * q + 2] = v.z; ra[4 * q + 3] = v.w;
            }
        }
        {
            bool v = (t >= 0) && (n >= dA);
            const float4* p = (const float4*)(hIn + (size_t)(v ? (t - dA) : tc) * 16);
#pragma unroll
            for (int q = 0; q < 4; ++q) {
                float4 x = p[q];
                pa[4 * q]     = v ? x.x : 0.f;
                pa[4 * q + 1] = v ? x.y : 0.f;
                pa[4 * q + 2] = v ? x.z : 0.f;
                pa[4 * q + 3] = v ? x.w : 0.f;
            }
        }

        float wa[16];
        gated(wfA, bfA, wgA, bgA, ra, pa, wa);

#pragma unroll
        for (int c = 0; c < 16; ++c) hmid[c][loc] = wa[c];

        if (loc >= dB) store_bf_row(HbfA, t, wa);   // t in [base, base+PPB)
    }
    __syncthreads();

    // ---- phase 2: layer B over [base, base+PPB) from LDS
#pragma unroll 1
    for (int k = 0; k < PPB / 256; ++k) {
        int loc2 = threadIdx.x + k * 256;
        int t = base + loc2;
        int n = t & (NPOS - 1);

        float ra[16], pa[16];
        bool v = (n >= dB);
#pragma unroll
        for (int c = 0; c < 16; ++c) {
            ra[c] = hmid[c][loc2 + dB];
            float x = hmid[c][loc2];
            pa[c] = v ? x : 0.f;
        }

        float wb[16];
        gated(wfB, bfB, wgB, bgB, ra, pa, wb);

        store_rows(hOut, HbfB, t, wb);
    }
}

// ================= final: MFMA skip-sum (bf16 H) + agg + MFMA logits =======
// (verbatim from R12 — validated at 210 µs)
__global__ __launch_bounds__(256, 2) void final_kernel_ds4(
    const unsigned short* __restrict__ Hbf,
    const float* __restrict__ Wsk,  const float* __restrict__ bskv,
    const float* __restrict__ Wagg, const float* __restrict__ bagg,
    const float* __restrict__ Wout, const float* __restrict__ bout,
    float* __restrict__ out)
{
    __shared__ float sv_lds[64][33];
    __shared__ unsigned short agg_bu[64 * 64];
    __shared__ float red_m[64][5];
    __shared__ float red_s[64][5];
    __shared__ float bsum[32];

    int tid  = threadIdx.x;
    int lane = tid & 63;
    int w    = tid >> 6;
    int posG = blockIdx.x * 64;
    int b    = posG >> LOG2N;
    int nb   = posG & (NPOS - 1);

    int lr = lane & 15;
    int lg = lane >> 4;

    if (tid < 32) {
        float s = 0.f;
#pragma unroll 1
        for (int i = 0; i < 19; ++i) s += bskv[i * 32 + tid];
        bsum[tid] = s;
    }

    int posGlob = posG + w * 16 + lr;

    f32x4 dsk0 = {0.f, 0.f, 0.f, 0.f};
    f32x4 dsk1 = {0.f, 0.f, 0.f, 0.f};

#pragma unroll
    for (int kt = 0; kt < 10; ++kt) {
        int i   = kt * 2 + (lg >> 1);
        int ic0 = (lg & 1) * 8;
        short8v bfr = {0, 0, 0, 0, 0, 0, 0, 0};
        short8v af0 = {0, 0, 0, 0, 0, 0, 0, 0};
        short8v af1 = {0, 0, 0, 0, 0, 0, 0, 0};
        if (i < 19) {
            bfr = *(const short8v*)(Hbf + (size_t)i * HBFE + (size_t)posGlob * 16 + ic0);

            const float4* wp0 = (const float4*)(Wsk + (size_t)i * 512 + (0 * 16 + lr) * 16 + ic0);
            const float4* wp1 = (const float4*)(Wsk + (size_t)i * 512 + (1 * 16 + lr) * 16 + ic0);
            float4 a0 = wp0[0], a1 = wp0[1];
            float4 c0v = wp1[0], c1v = wp1[1];
            af0[0] = (short)bf16rne(a0.x); af0[1] = (short)bf16rne(a0.y);
            af0[2] = (short)bf16rne(a0.z); af0[3] = (short)bf16rne(a0.w);
            af0[4] = (short)bf16rne(a1.x); af0[5] = (short)bf16rne(a1.y);
            af0[6] = (short)bf16rne(a1.z); af0[7] = (short)bf16rne(a1.w);
            af1[0] = (short)bf16rne(c0v.x); af1[1] = (short)bf16rne(c0v.y);
            af1[2] = (short)bf16rne(c0v.z); af1[3] = (short)bf16rne(c0v.w);
            af1[4] = (short)bf16rne(c1v.x); af1[5] = (short)bf16rne(c1v.y);
            af1[6] = (short)bf16rne(c1v.z); af1[7] = (short)bf16rne(c1v.w);
        }
        dsk0 = __builtin_amdgcn_mfma_f32_16x16x32_bf16(af0, bfr, dsk0, 0, 0, 0);
        dsk1 = __builtin_amdgcn_mfma_f32_16x16x32_bf16(af1, bfr, dsk1, 0, 0, 0);
    }

    __syncthreads();

    {
        int posL = w * 16 + lr;
#pragma unroll
        for (int r = 0; r < 4; ++r) {
            int sc0 = 0 * 16 + lg * 4 + r;
            int sc1 = 1 * 16 + lg * 4 + r;
            sv_lds[posL][sc0] = fmaxf(dsk0[r] + bsum[sc0], 0.f);
            sv_lds[posL][sc1] = fmaxf(dsk1[r] + bsum[sc1], 0.f);
        }
    }
    __syncthreads();

    {
        float sv[32];
#pragma unroll
        for (int sch = 0; sch < 32; ++sch) sv[sch] = sv_lds[lane][sch];

        float r16[16];
#pragma unroll
        for (int a = 0; a < 16; ++a) {
            int ac = w * 16 + a;
            float acc = bagg[ac];
#pragma unroll
            for (int sch = 0; sch < 32; ++sch)
                acc = fmaf(Wagg[ac * 32 + sch], sv[sch], acc);
            r16[a] = fmaxf(acc, 0.f);
        }
#pragma unroll
        for (int q = 0; q < 8; ++q) {
            unsigned pk = (unsigned)bf16rne(r16[2 * q]) |
                          ((unsigned)bf16rne(r16[2 * q + 1]) << 16);
            int icbyte = (w * 16 + 2 * q) * 2;
            int addr   = lane * 128 + (icbyte ^ ((lane & 7) << 4));
            *(unsigned*)(&agg_bu[addr >> 1]) = pk;
        }
    }
    __syncthreads();

    int c0 = w * 64;
    short8v afr[4][2];
#pragma unroll
    for (int ct = 0; ct < 4; ++ct) {
#pragma unroll
        for (int kf = 0; kf < 2; ++kf) {
            int cls = c0 + ct * 16 + lr;
            int k0  = kf * 32 + lg * 8;
            const float4* wp = (const float4*)(Wout + (size_t)cls * 64 + k0);
            float4 w0 = wp[0], w1 = wp[1];
            short8v af;
            af[0] = (short)bf16rne(w0.x); af[1] = (short)bf16rne(w0.y);
            af[2] = (short)bf16rne(w0.z); af[3] = (short)bf16rne(w0.w);
            af[4] = (short)bf16rne(w1.x); af[5] = (short)bf16rne(w1.y);
            af[6] = (short)bf16rne(w1.z); af[7] = (short)bf16rne(w1.w);
            afr[ct][kf] = af;
        }
    }

    f32x4 acc[4][4];
#pragma unroll
    for (int pt = 0; pt < 4; ++pt) {
        int pos = pt * 16 + lr;
        int sw  = (pos & 7) << 4;
        const short8v* bp0 = (const short8v*)(&agg_bu[(pos * 128 + ((0 * 64 + lg * 16) ^ sw)) >> 1]);
        const short8v* bp1 = (const short8v*)(&agg_bu[(pos * 128 + ((1 * 64 + lg * 16) ^ sw)) >> 1]);
        short8v bf0 = *bp0;
        short8v bf1 = *bp1;
#pragma unroll
        for (int ct = 0; ct < 4; ++ct) {
            f32x4 c;
#pragma unroll
            for (int r = 0; r < 4; ++r) c[r] = bout[c0 + ct * 16 + lg * 4 + r];
            c = __builtin_amdgcn_mfma_f32_16x16x32_bf16(afr[ct][0], bf0, c, 0, 0, 0);
            c = __builtin_amdgcn_mfma_f32_16x16x32_bf16(afr[ct][1], bf1, c, 0, 0, 0);
            acc[pt][ct] = c;
        }
    }

#pragma unroll
    for (int pt = 0; pt < 4; ++pt) {
        float m = -1e30f;
#pragma unroll
        for (int ct = 0; ct < 4; ++ct)
#pragma unroll
            for (int r = 0; r < 4; ++r) m = fmaxf(m, acc[pt][ct][r]);
        m = fmaxf(m, __shfl_xor(m, 16));
        m = fmaxf(m, __shfl_xor(m, 32));
        float s = 0.f;
#pragma unroll
        for (int ct = 0; ct < 4; ++ct)
#pragma unroll
            for (int r = 0; r < 4; ++r) s += __expf(acc[pt][ct][r] - m);
        s += __shfl_xor(s, 16);
        s += __shfl_xor(s, 32);
        int pos = pt * 16 + lr;
        red_m[pos][w] = m;
        red_s[pos][w] = s;
    }
    __syncthreads();

#pragma unroll
    for (int pt = 0; pt < 4; ++pt) {
        int pos = pt * 16 + lr;
        float M = fmaxf(fmaxf(red_m[pos][0], red_m[pos][1]),
                        fmaxf(red_m[pos][2], red_m[pos][3]));
        float S = 0.f;
#pragma unroll
        for (int k = 0; k < 4; ++k) S += red_s[pos][k] * __expf(red_m[pos][k] - M);
        float logZ = M + __logf(S);

        int n = nb + pos;
#pragma unroll
        for (int ct = 0; ct < 4; ++ct) {
#pragma unroll
            for (int r = 0; r < 4; ++r) {
                int cls = c0 + ct * 16 + lg * 4 + r;
                out[((size_t)(b * 256 + cls)) * NPOS + n] = acc[pt][ct][r] - logZ;
            }
        }
    }
}

// ======================================================================
// R8 fallback path (channel-major, skip-RMW) — kept verbatim
// ======================================================================
__global__ __launch_bounds__(256) void init_kernel2(
    const int* __restrict__ x_int, const float* __restrict__ W0,
    const float* __restrict__ b0, float* __restrict__ h)
{
    int t0 = (blockIdx.x * 256 + threadIdx.x) * 2;
    int n0 = t0 & (NPOS - 1);
    const float sc = 1.f / 32768.f;
    float xs0  = (n0 >= 1) ? (float)x_int[t0 - 1] * sc : 0.f;
    float xs1  = (float)x_int[t0] * sc;
    float xsp0 = (n0 >= 2) ? (float)x_int[t0 - 2] * sc : 0.f;
    float xsp1 = xs0;
#pragma unroll
    for (int c = 0; c < 16; ++c) {
        float2 o;
        o.x = xs0 + W0[c * 2 + 0] * xsp0 + W0[c * 2 + 1] * xs0 + b0[c];
        o.y = xs1 + W0[c * 2 + 0] * xsp1 + W0[c * 2 + 1] * xs1 + b0[c];
        *(float2*)(h + (size_t)c * TOTAL + t0) = o;
    }
}

__global__ __launch_bounds__(256, 2) void layer_kernel2(
    const float* __restrict__ hIn, float* __restrict__ hOut,
    float* __restrict__ skip,
    const float* __restrict__ wf, const float* __restrict__ bfv,
    const float* __restrict__ wg, const float* __restrict__ bgv,
    const float* __restrict__ wsk, const float* __restrict__ bskv,
    int d, int firstLayer)
{
    int t0 = (blockIdx.x * 256 + threadIdx.x) * 2;
    int n0 = t0 & (NPOS - 1);

    float2 hc[16], hp[16];
#pragma unroll
    for (int ic = 0; ic < 16; ++ic)
        hc[ic] = *(const float2*)(hIn + (size_t)ic * TOTAL + t0);

    if (d == 1) {
        bool v = (n0 >= 1);
        int tm = v ? (t0 - 1) : t0;
#pragma unroll
        for (int ic = 0; ic < 16; ++ic) {
            float x = hIn[(size_t)ic * TOTAL + tm];
            hp[ic].x = v ? x : 0.f;
            hp[ic].y = hc[ic].x;
        }
    } else {
        bool v = (n0 >= d);
        int tm = v ? (t0 - d) : t0;
#pragma unroll
        for (int ic = 0; ic < 16; ++ic) {
            float2 x = *(const float2*)(hIn + (size_t)ic * TOTAL + tm);
            hp[ic].x = v ? x.x : 0.f;
            hp[ic].y = v ? x.y : 0.f;
        }
    }

    float2 fa[16], ga[16];
#pragma unroll
    for (int c = 0; c < 16; ++c) {
        fa[c].x = fa[c].y = bfv[c];
        ga[c].x = ga[c].y = bgv[c];
    }
#pragma unroll
    for (int c = 0; c < 16; ++c) {
#pragma unroll
        for (int ic = 0; ic < 16; ++ic) {
            float wf0 = wf[(c * 16 + ic) * 2 + 0];
            float wf1 = wf[(c * 16 + ic) * 2 + 1];
            float wg0 = wg[(c * 16 + ic) * 2 + 0];
            float wg1 = wg[(c * 16 + ic) * 2 + 1];
            fa[c].x = fmaf(wf0, hp[ic].x, fa[c].x);
            fa[c].x = fmaf(wf1, hc[ic].x, fa[c].x);
            fa[c].y = fmaf(wf0, hp[ic].y, fa[c].y);
            fa[c].y = fmaf(wf1, hc[ic].y, fa[c].y);
            ga[c].x = fmaf(wg0, hp[ic].x, ga[c].x);
            ga[c].x = fmaf(wg1, hc[ic].x, ga[c].x);
            ga[c].y = fmaf(wg0, hp[ic].y, ga[c].y);
            ga[c].y = fmaf(wg1, hc[ic].y, ga[c].y);
        }
    }

#pragma unroll
    for (int c = 0; c < 16; ++c) {
        float2 o;
        o.x = fmaf(fast_tanh(fa[c].x), fast_sigmoid(ga[c].x), hc[c].x);
        o.y = fmaf(fast_tanh(fa[c].y), fast_sigmoid(ga[c].y), hc[c].y);
        *(float2*)(hOut + (size_t)c * TOTAL + t0) = o;
    }

#pragma unroll
    for (int sch = 0; sch < 32; ++sch) {
        float2 acc;
        acc.x = acc.y = bskv[sch];
#pragma unroll
        for (int ic = 0; ic < 16; ++ic) {
            float wv = wsk[sch * 16 + ic];
            acc.x = fmaf(wv, hc[ic].x, acc.x);
            acc.y = fmaf(wv, hc[ic].y, acc.y);
        }
        float* sp = skip + (size_t)sch * TOTAL + t0;
        if (firstLayer) {
            *(float2*)sp = acc;
        } else {
            float2 old = *(const float2*)sp;
            acc.x += old.x; acc.y += old.y;
            *(float2*)sp = acc;
        }
    }
}

__global__ __launch_bounds__(256, 2) void final_kernel(
    const float* __restrict__ skip,
    const float* __restrict__ Wagg, const float* __restrict__ bagg,
    const float* __restrict__ Wout, const float* __restrict__ bout,
    float* __restrict__ out)
{
    __shared__ unsigned short agg_bu[64 * 64];
    __shared__ float red_m[64][5];
    __shared__ float red_s[64][5];

    int tid  = threadIdx.x;
    int lane = tid & 63;
    int w    = tid >> 6;
    int posG = blockIdx.x * 64;
    int b    = posG >> LOG2N;
    int nb   = posG & (NPOS - 1);

    {
        int pos = posG + lane;
        float sv[32];
#pragma unroll
        for (int sch = 0; sch < 32; ++sch)
            sv[sch] = fmaxf(skip[(size_t)sch * TOTAL + pos], 0.f);

        float r16[16];
#pragma unroll
        for (int a = 0; a < 16; ++a) {
            int ac = w * 16 + a;
            float acc = bagg[ac];
#pragma unroll
            for (int sch = 0; sch < 32; ++sch)
                acc = fmaf(Wagg[ac * 32 + sch], sv[sch], acc);
            r16[a] = fmaxf(acc, 0.f);
        }
#pragma unroll
        for (int q = 0; q < 8; ++q) {
            unsigned pk = (unsigned)bf16rne(r16[2 * q]) |
                          ((unsigned)bf16rne(r16[2 * q + 1]) << 16);
            int icbyte = (w * 16 + 2 * q) * 2;
            int addr   = lane * 128 + (icbyte ^ ((lane & 7) << 4));
            *(unsigned*)(&agg_bu[addr >> 1]) = pk;
        }
    }
    __syncthreads();

    int lr = lane & 15;
    int lg = lane >> 4;
    int c0 = w * 64;
    short8v afr[4][2];
#pragma unroll
    for (int ct = 0; ct < 4; ++ct) {
#pragma unroll
        for (int kf = 0; kf < 2; ++kf) {
            int cls = c0 + ct * 16 + lr;
            int k0  = kf * 32 + lg * 8;
            const float4* wp = (const float4*)(Wout + (size_t)cls * 64 + k0);
            float4 w0 = wp[0], w1 = wp[1];
            short8v af;
            af[0] = (short)bf16rne(w0.x); af[1] = (short)bf16rne(w0.y);
            af[2] = (short)bf16rne(w0.z); af[3] = (short)bf16rne(w0.w);
            af[4] = (short)bf16rne(w1.x); af[5] = (short)bf16rne(w1.y);
            af[6] = (short)bf16rne(w1.z); af[7] = (short)bf16rne(w1.w);
            afr[ct][kf] = af;
        }
    }

    f32x4 acc[4][4];
#pragma unroll
    for (int pt = 0; pt < 4; ++pt) {
        int pos = pt * 16 + lr;
        int sw  = (pos & 7) << 4;
        const short8v* bp0 = (const short8v*)(&agg_bu[(pos * 128 + ((0 * 64 + lg * 16) ^ sw)) >> 1]);
        const short8v* bp1 = (const short8v*)(&agg_bu[(pos * 128 + ((1 * 64 + lg * 16) ^ sw)) >> 1]);
        short8v bf0 = *bp0;
        short8v bf1 = *bp1;
#pragma unroll
        for (int ct = 0; ct < 4; ++ct) {
            f32x4 c;
#pragma unroll
            for (int r = 0; r < 4; ++r) c[r] = bout[c0 + ct * 16 + lg * 4 + r];
            c = __builtin_amdgcn_mfma_f32_16x16x32_bf16(afr[ct][0], bf0, c, 0, 0, 0);
            c = __builtin_amdgcn_mfma_f32_16x16x32_bf16(afr[ct][1], bf1, c, 0, 0, 0);
            acc[pt][ct] = c;
        }
    }

#pragma unroll
    for (int pt = 0; pt < 4; ++pt) {
        float m = -1e30f;
#pragma unroll
        for (int ct = 0; ct < 4; ++ct)
#pragma unroll
            for (int r = 0; r < 4; ++r) m = fmaxf(m, acc[pt][ct][r]);
        m = fmaxf(m, __shfl_xor(m, 16));
        m = fmaxf(m, __shfl_xor(m, 32));
        float s = 0.f;
#pragma unroll
        for (int ct = 0; ct < 4; ++ct)
#pragma unroll
            for (int r = 0; r < 4; ++r) s += __expf(acc[pt][ct][r] - m);
        s += __shfl_xor(s, 16);
        s += __shfl_xor(s, 32);
        int pos = pt * 16 + lr;
        red_m[pos][w] = m;
        red_s[pos][w] = s;
    }
    __syncthreads();

#pragma unroll
    for (int pt = 0; pt < 4; ++pt) {
        int pos = pt * 16 + lr;
        float M = fmaxf(fmaxf(red_m[pos][0], red_m[pos][1]),
                        fmaxf(red_m[pos][2], red_m[pos][3]));
        float S = 0.f;
#pragma unroll
        for (int k = 0; k < 4; ++k) S += red_s[pos][k] * __expf(red_m[pos][k] - M);
        float logZ = M + __logf(S);

        int n = nb + pos;
#pragma unroll
        for (int ct = 0; ct < 4; ++ct) {
#pragma unroll
            for (int r = 0; r < 4; ++r) {
                int cls = c0 + ct * 16 + lg * 4 + r;
                out[((size_t)(b * 256 + cls)) * NPOS + n] = acc[pt][ct][r] - logZ;
            }
        }
    }
}

extern "C" void kernel_launch(void* const* d_in, const int* in_sizes, int n_in,
                              void* d_out, int out_size, void* d_ws, size_t ws_size,
                              hipStream_t stream)
{
    const int*   x_int = (const int*)  d_in[0];
    const float* W0    = (const float*)d_in[1];
    const float* b0    = (const float*)d_in[2];
    const float* Wf    = (const float*)d_in[3];
    const float* bfv   = (const float*)d_in[4];
    const float* Wg    = (const float*)d_in[5];
    const float* bgv   = (const float*)d_in[6];
    const float* Wsk   = (const float*)d_in[7];
    const float* bskv  = (const float*)d_in[8];
    const float* Wagg  = (const float*)d_in[9];
    const float* bagg  = (const float*)d_in[10];
    const float* Wout  = (const float*)d_in[11];
    const float* bout  = (const float*)d_in[12];
    float* out = (float*)d_out;

    const size_t needDefer = 19 * HBFE * sizeof(unsigned short)   // 152 MiB bf16 H
                           + 2 * HE * sizeof(float);              // 32 MiB fp32 ping-pong

    if (ws_size >= needDefer) {
        // ---------- fused-pair defer-skip path ----------
        unsigned short* Hbf = (unsigned short*)d_ws;
        float* hA = (float*)((char*)d_ws + 19 * HBFE * sizeof(unsigned short));
        float* hB = hA + HE;

        init_kernel_rm1<<<TOTAL / 256, 256, 0, stream>>>(x_int, W0, b0, hA, Hbf);

        float* hin = hA;
        float* hout = hB;
        for (int p = 0; p < 9; ++p) {
            int iA = 2 * p, iB = 2 * p + 1;
            int dA = 1 << ((iA + 1) % 10);
            int dB = 1 << ((iB + 1) % 10);
            pair_kernel<<<TOTAL / PPB, 256, 0, stream>>>(
                hin, hout,
                Hbf + (size_t)(iA + 1) * HBFE, Hbf + (size_t)(iB + 1) * HBFE,
                Wf + (size_t)iA * 512, bfv + (size_t)iA * 16,
                Wg + (size_t)iA * 512, bgv + (size_t)iA * 16,
                Wf + (size_t)iB * 512, bfv + (size_t)iB * 16,
                Wg + (size_t)iB * 512, bgv + (size_t)iB * 16,
                dA, dB);
            float* tmp = hin; hin = hout; hout = tmp;
        }
        final_kernel_ds4<<<TOTAL / 64, 256, 0, stream>>>(
            Hbf, Wsk, bskv, Wagg, bagg, Wout, bout, out);
    } else {
        // ---------- R8 fallback (channel-major) ----------
        const int grid2 = TOTAL / (256 * 2);
        const size_t skE = (size_t)32 * TOTAL;
        float* skipb = (float*)d_ws;
        float *hA, *hB;
        if (ws_size >= (skE + 2 * HE) * sizeof(float)) {
            hA = skipb + skE;
            hB = hA + HE;
        } else {
            hA = out + ((size_t)out_size - 2 * HE);
            hB = hA + HE;
        }

        init_kernel2<<<grid2, 256, 0, stream>>>(x_int, W0, b0, hA);
        float* hin = hA;
        float* hout = hB;
        for (int i = 0; i < 19; ++i) {
            int d = 1 << ((i + 1) % 10);
            layer_kernel2<<<grid2, 256, 0, stream>>>(
                hin, hout, skipb,
                Wf + (size_t)i * 512, bfv + (size_t)i * 16,
                Wg + (size_t)i * 512, bgv + (size_t)i * 16,
                Wsk + (size_t)i * 512, bskv + (size_t)i * 32,
                d, (i == 0) ? 1 : 0);
            float* tmp = hin; hin = hout; hout = tmp;
        }
        final_kernel<<<TOTAL / 64, 256, 0, stream>>>(
            skipb, Wagg, bagg, Wout, bout, out);
    }
}

// Round 14
// 1071.927 us; speedup vs baseline: 1.8030x; 1.8030x over previous
//
#include <hip/hip_runtime.h>
#include <math.h>
#include <stdint.h>

#define NPOS  32768
#define LOG2N 15
#define BATCH 8
#define TOTAL (BATCH * NPOS)          // 262144 positions
#define HE    ((size_t)16 * TOTAL)    // one fp32 h buffer, elements (16 MiB)
#define HBFE  ((size_t)16 * TOTAL)    // one bf16 H buffer, elements (8 MiB)

typedef __attribute__((ext_vector_type(8))) short short8v;  // 8 bf16 = 4 VGPR
typedef __attribute__((ext_vector_type(4))) float f32x4;    // MFMA C/D

__device__ __forceinline__ float fast_tanh(float x) {
    float t = __expf(-2.f * x);
    return fmaf(2.f, __builtin_amdgcn_rcpf(1.f + t), -1.f);
}
__device__ __forceinline__ float fast_sigmoid(float x) {
    return __builtin_amdgcn_rcpf(1.f + __expf(-x));
}
__device__ __forceinline__ unsigned short bf16rne(float x) {
    unsigned u = __float_as_uint(x);
    u = (u + 0x7fffu + ((u >> 16) & 1u)) >> 16;
    return (unsigned short)u;
}

__device__ __forceinline__ void store_bf_row(unsigned short* __restrict__ bf,
                                             int t, const float* w)
{
    unsigned pk[8];
#pragma unroll
    for (int q = 0; q < 8; ++q)
        pk[q] = (unsigned)bf16rne(w[2 * q]) | ((unsigned)bf16rne(w[2 * q + 1]) << 16);
    uint4* ob = (uint4*)(bf + (size_t)t * 16);
    ob[0] = make_uint4(pk[0], pk[1], pk[2], pk[3]);
    ob[1] = make_uint4(pk[4], pk[5], pk[6], pk[7]);
}

__device__ __forceinline__ void store_rows(float* __restrict__ fp,
                                           unsigned short* __restrict__ bf,
                                           int t, const float* w)
{
    float4* o = (float4*)(fp + (size_t)t * 16);
#pragma unroll
    for (int q = 0; q < 4; ++q)
        o[q] = make_float4(w[4 * q], w[4 * q + 1], w[4 * q + 2], w[4 * q + 3]);
    store_bf_row(bf, t, w);
}

// ================= init: h_0 (fp32 row-major) + Hbf_0 ======================
__global__ __launch_bounds__(256) void init_kernel_rm1(
    const int* __restrict__ x_int, const float* __restrict__ W0,
    const float* __restrict__ b0,
    float* __restrict__ hfp, unsigned short* __restrict__ hbf)
{
    int t = blockIdx.x * 256 + threadIdx.x;
    int n = t & (NPOS - 1);
    const float sc = 1.f / 32768.f;
    float xs  = (n >= 1) ? (float)x_int[t - 1] * sc : 0.f;
    float xsp = (n >= 2) ? (float)x_int[t - 2] * sc : 0.f;
    float w[16];
#pragma unroll
    for (int c = 0; c < 16; ++c)
        w[c] = xs + W0[c * 2 + 0] * xsp + W0[c * 2 + 1] * xs + b0[c];
    store_rows(hfp, hbf, t, w);
}

// ================= residual layer, channel-split (8 ch/thread) =============
// Wave w of 4: positions blk*128 + (w>>1)*64 + lane, channels [(w&1)*8, +8).
// Halved serial FMA chain + 2048 blocks -> 6 waves/SIMD: latency attack.
__global__ __launch_bounds__(256, 6) void layer_kernel_cs(
    const float* __restrict__ hIn, float* __restrict__ hOut,
    unsigned short* __restrict__ hbfOut,
    const float* __restrict__ wf, const float* __restrict__ bfv,
    const float* __restrict__ wg, const float* __restrict__ bgv,
    int d)
{
    int wv   = threadIdx.x >> 6;
    int lane = threadIdx.x & 63;
    int t    = blockIdx.x * 128 + (wv >> 1) * 64 + lane;
    int c0   = (wv & 1) * 8;          // wave-uniform channel half
    int n    = t & (NPOS - 1);

    float ra[16], pa[16];
    {
        const float4* p = (const float4*)(hIn + (size_t)t * 16);
#pragma unroll
        for (int q = 0; q < 4; ++q) {
            float4 v = p[q];
            ra[4 * q] = v.x; ra[4 * q + 1] = v.y;
            ra[4 * q + 2] = v.z; ra[4 * q + 3] = v.w;
        }
    }
    {
        bool v = (n >= d);
        const float4* p = (const float4*)(hIn + (size_t)(v ? (t - d) : t) * 16);
#pragma unroll
        for (int q = 0; q < 4; ++q) {
            float4 x = p[q];
            pa[4 * q]     = v ? x.x : 0.f;
            pa[4 * q + 1] = v ? x.y : 0.f;
            pa[4 * q + 2] = v ? x.z : 0.f;
            pa[4 * q + 3] = v ? x.w : 0.f;
        }
    }

    float wa[8];
#pragma unroll
    for (int j = 0; j < 8; ++j) {
        int c = c0 + j;
        float fa = bfv[c], ga = bgv[c];
#pragma unroll
        for (int ic = 0; ic < 16; ++ic) {
            fa = fmaf(wf[(c * 16 + ic) * 2 + 0], pa[ic], fa);
            fa = fmaf(wf[(c * 16 + ic) * 2 + 1], ra[ic], fa);
            ga = fmaf(wg[(c * 16 + ic) * 2 + 0], pa[ic], ga);
            ga = fmaf(wg[(c * 16 + ic) * 2 + 1], ra[ic], ga);
        }
        wa[j] = fmaf(fast_tanh(fa), fast_sigmoid(ga), ra[c]);
    }

    // fp32 store (32B) + bf16 store (16B), disjoint per thread
    float4* o = (float4*)(hOut + (size_t)t * 16 + c0);
    o[0] = make_float4(wa[0], wa[1], wa[2], wa[3]);
    o[1] = make_float4(wa[4], wa[5], wa[6], wa[7]);

    unsigned pk[4];
#pragma unroll
    for (int q = 0; q < 4; ++q)
        pk[q] = (unsigned)bf16rne(wa[2 * q]) | ((unsigned)bf16rne(wa[2 * q + 1]) << 16);
    *(uint4*)(hbfOut + (size_t)t * 16 + c0) = make_uint4(pk[0], pk[1], pk[2], pk[3]);
}

// ================= final: MFMA skip-sum (bf16 H) + agg + MFMA logits =======
// (verbatim — validated at ~210 µs)
__global__ __launch_bounds__(256, 2) void final_kernel_ds4(
    const unsigned short* __restrict__ Hbf,
    const float* __restrict__ Wsk,  const float* __restrict__ bskv,
    const float* __restrict__ Wagg, const float* __restrict__ bagg,
    const float* __restrict__ Wout, const float* __restrict__ bout,
    float* __restrict__ out)
{
    __shared__ float sv_lds[64][33];
    __shared__ unsigned short agg_bu[64 * 64];
    __shared__ float red_m[64][5];
    __shared__ float red_s[64][5];
    __shared__ float bsum[32];

    int tid  = threadIdx.x;
    int lane = tid & 63;
    int w    = tid >> 6;
    int posG = blockIdx.x * 64;
    int b    = posG >> LOG2N;
    int nb   = posG & (NPOS - 1);

    int lr = lane & 15;
    int lg = lane >> 4;

    if (tid < 32) {
        float s = 0.f;
#pragma unroll 1
        for (int i = 0; i < 19; ++i) s += bskv[i * 32 + tid];
        bsum[tid] = s;
    }

    int posGlob = posG + w * 16 + lr;

    f32x4 dsk0 = {0.f, 0.f, 0.f, 0.f};
    f32x4 dsk1 = {0.f, 0.f, 0.f, 0.f};

#pragma unroll
    for (int kt = 0; kt < 10; ++kt) {
        int i   = kt * 2 + (lg >> 1);
        int ic0 = (lg & 1) * 8;
        short8v bfr = {0, 0, 0, 0, 0, 0, 0, 0};
        short8v af0 = {0, 0, 0, 0, 0, 0, 0, 0};
        short8v af1 = {0, 0, 0, 0, 0, 0, 0, 0};
        if (i < 19) {
            bfr = *(const short8v*)(Hbf + (size_t)i * HBFE + (size_t)posGlob * 16 + ic0);

            const float4* wp0 = (const float4*)(Wsk + (size_t)i * 512 + (0 * 16 + lr) * 16 + ic0);
            const float4* wp1 = (const float4*)(Wsk + (size_t)i * 512 + (1 * 16 + lr) * 16 + ic0);
            float4 a0 = wp0[0], a1 = wp0[1];
            float4 c0v = wp1[0], c1v = wp1[1];
            af0[0] = (short)bf16rne(a0.x); af0[1] = (short)bf16rne(a0.y);
            af0[2] = (short)bf16rne(a0.z); af0[3] = (short)bf16rne(a0.w);
            af0[4] = (short)bf16rne(a1.x); af0[5] = (short)bf16rne(a1.y);
            af0[6] = (short)bf16rne(a1.z); af0[7] = (short)bf16rne(a1.w);
            af1[0] = (short)bf16rne(c0v.x); af1[1] = (short)bf16rne(c0v.y);
            af1[2] = (short)bf16rne(c0v.z); af1[3] = (short)bf16rne(c0v.w);
            af1[4] = (short)bf16rne(c1v.x); af1[5] = (short)bf16rne(c1v.y);
            af1[6] = (short)bf16rne(c1v.z); af1[7] = (short)bf16rne(c1v.w);
        }
        dsk0 = __builtin_amdgcn_mfma_f32_16x16x32_bf16(af0, bfr, dsk0, 0, 0, 0);
        dsk1 = __builtin_amdgcn_mfma_f32_16x16x32_bf16(af1, bfr, dsk1, 0, 0, 0);
    }

    __syncthreads();

    {
        int posL = w * 16 + lr;
#pragma unroll
        for (int r = 0; r < 4; ++r) {
            int sc0 = 0 * 16 + lg * 4 + r;
            int sc1 = 1 * 16 + lg * 4 + r;
            sv_lds[posL][sc0] = fmaxf(dsk0[r] + bsum[sc0], 0.f);
            sv_lds[posL][sc1] = fmaxf(dsk1[r] + bsum[sc1], 0.f);
        }
    }
    __syncthreads();

    {
        float sv[32];
#pragma unroll
        for (int sch = 0; sch < 32; ++sch) sv[sch] = sv_lds[lane][sch];

        float r16[16];
#pragma unroll
        for (int a = 0; a < 16; ++a) {
            int ac = w * 16 + a;
            float acc = bagg[ac];
#pragma unroll
            for (int sch = 0; sch < 32; ++sch)
                acc = fmaf(Wagg[ac * 32 + sch], sv[sch], acc);
            r16[a] = fmaxf(acc, 0.f);
        }
#pragma unroll
        for (int q = 0; q < 8; ++q) {
            unsigned pk = (unsigned)bf16rne(r16[2 * q]) |
                          ((unsigned)bf16rne(r16[2 * q + 1]) << 16);
            int icbyte = (w * 16 + 2 * q) * 2;
            int addr   = lane * 128 + (icbyte ^ ((lane & 7) << 4));
            *(unsigned*)(&agg_bu[addr >> 1]) = pk;
        }
    }
    __syncthreads();

    int c0 = w * 64;
    short8v afr[4][2];
#pragma unroll
    for (int ct = 0; ct < 4; ++ct) {
#pragma unroll
        for (int kf = 0; kf < 2; ++kf) {
            int cls = c0 + ct * 16 + lr;
            int k0  = kf * 32 + lg * 8;
            const float4* wp = (const float4*)(Wout + (size_t)cls * 64 + k0);
            float4 w0 = wp[0], w1 = wp[1];
            short8v af;
            af[0] = (short)bf16rne(w0.x); af[1] = (short)bf16rne(w0.y);
            af[2] = (short)bf16rne(w0.z); af[3] = (short)bf16rne(w0.w);
            af[4] = (short)bf16rne(w1.x); af[5] = (short)bf16rne(w1.y);
            af[6] = (short)bf16rne(w1.z); af[7] = (short)bf16rne(w1.w);
            afr[ct][kf] = af;
        }
    }

    f32x4 acc[4][4];
#pragma unroll
    for (int pt = 0; pt < 4; ++pt) {
        int pos = pt * 16 + lr;
        int sw  = (pos & 7) << 4;
        const short8v* bp0 = (const short8v*)(&agg_bu[(pos * 128 + ((0 * 64 + lg * 16) ^ sw)) >> 1]);
        const short8v* bp1 = (const short8v*)(&agg_bu[(pos * 128 + ((1 * 64 + lg * 16) ^ sw)) >> 1]);
        short8v bf0 = *bp0;
        short8v bf1 = *bp1;
#pragma unroll
        for (int ct = 0; ct < 4; ++ct) {
            f32x4 c;
#pragma unroll
            for (int r = 0; r < 4; ++r) c[r] = bout[c0 + ct * 16 + lg * 4 + r];
            c = __builtin_amdgcn_mfma_f32_16x16x32_bf16(afr[ct][0], bf0, c, 0, 0, 0);
            c = __builtin_amdgcn_mfma_f32_16x16x32_bf16(afr[ct][1], bf1, c, 0, 0, 0);
            acc[pt][ct] = c;
        }
    }

#pragma unroll
    for (int pt = 0; pt < 4; ++pt) {
        float m = -1e30f;
#pragma unroll
        for (int ct = 0; ct < 4; ++ct)
#pragma unroll
            for (int r = 0; r < 4; ++r) m = fmaxf(m, acc[pt][ct][r]);
        m = fmaxf(m, __shfl_xor(m, 16));
        m = fmaxf(m, __shfl_xor(m, 32));
        float s = 0.f;
#pragma unroll
        for (int ct = 0; ct < 4; ++ct)
#pragma unroll
            for (int r = 0; r < 4; ++r) s += __expf(acc[pt][ct][r] - m);
        s += __shfl_xor(s, 16);
        s += __shfl_xor(s, 32);
        int pos = pt * 16 + lr;
        red_m[pos][w] = m;
        red_s[pos][w] = s;
    }
    __syncthreads();

#pragma unroll
    for (int pt = 0; pt < 4; ++pt) {
        int pos = pt * 16 + lr;
        float M = fmaxf(fmaxf(red_m[pos][0], red_m[pos][1]),
                        fmaxf(red_m[pos][2], red_m[pos][3]));
        float S = 0.f;
#pragma unroll
        for (int k = 0; k < 4; ++k) S += red_s[pos][k] * __expf(red_m[pos][k] - M);
        float logZ = M + __logf(S);

        int n = nb + pos;
#pragma unroll
        for (int ct = 0; ct < 4; ++ct) {
#pragma unroll
            for (int r = 0; r < 4; ++r) {
                int cls = c0 + ct * 16 + lg * 4 + r;
                out[((size_t)(b * 256 + cls)) * NPOS + n] = acc[pt][ct][r] - logZ;
            }
        }
    }
}

// ======================================================================
// R8 fallback path (channel-major, skip-RMW) — kept verbatim
// ======================================================================
__global__ __launch_bounds__(256) void init_kernel2(
    const int* __restrict__ x_int, const float* __restrict__ W0,
    const float* __restrict__ b0, float* __restrict__ h)
{
    int t0 = (blockIdx.x * 256 + threadIdx.x) * 2;
    int n0 = t0 & (NPOS - 1);
    const float sc = 1.f / 32768.f;
    float xs0  = (n0 >= 1) ? (float)x_int[t0 - 1] * sc : 0.f;
    float xs1  = (float)x_int[t0] * sc;
    float xsp0 = (n0 >= 2) ? (float)x_int[t0 - 2] * sc : 0.f;
    float xsp1 = xs0;
#pragma unroll
    for (int c = 0; c < 16; ++c) {
        float2 o;
        o.x = xs0 + W0[c * 2 + 0] * xsp0 + W0[c * 2 + 1] * xs0 + b0[c];
        o.y = xs1 + W0[c * 2 + 0] * xsp1 + W0[c * 2 + 1] * xs1 + b0[c];
        *(float2*)(h + (size_t)c * TOTAL + t0) = o;
    }
}

__global__ __launch_bounds__(256, 2) void layer_kernel2(
    const float* __restrict__ hIn, float* __restrict__ hOut,
    float* __restrict__ skip,
    const float* __restrict__ wf, const float* __restrict__ bfv,
    const float* __restrict__ wg, const float* __restrict__ bgv,
    const float* __restrict__ wsk, const float* __restrict__ bskv,
    int d, int firstLayer)
{
    int t0 = (blockIdx.x * 256 + threadIdx.x) * 2;
    int n0 = t0 & (NPOS - 1);

    float2 hc[16], hp[16];
#pragma unroll
    for (int ic = 0; ic < 16; ++ic)
        hc[ic] = *(const float2*)(hIn + (size_t)ic * TOTAL + t0);

    if (d == 1) {
        bool v = (n0 >= 1);
        int tm = v ? (t0 - 1) : t0;
#pragma unroll
        for (int ic = 0; ic < 16; ++ic) {
            float x = hIn[(size_t)ic * TOTAL + tm];
            hp[ic].x = v ? x : 0.f;
            hp[ic].y = hc[ic].x;
        }
    } else {
        bool v = (n0 >= d);
        int tm = v ? (t0 - d) : t0;
#pragma unroll
        for (int ic = 0; ic < 16; ++ic) {
            float2 x = *(const float2*)(hIn + (size_t)ic * TOTAL + tm);
            hp[ic].x = v ? x.x : 0.f;
            hp[ic].y = v ? x.y : 0.f;
        }
    }

    float2 fa[16], ga[16];
#pragma unroll
    for (int c = 0; c < 16; ++c) {
        fa[c].x = fa[c].y = bfv[c];
        ga[c].x = ga[c].y = bgv[c];
    }
#pragma unroll
    for (int c = 0; c < 16; ++c) {
#pragma unroll
        for (int ic = 0; ic < 16; ++ic) {
            float wf0 = wf[(c * 16 + ic) * 2 + 0];
            float wf1 = wf[(c * 16 + ic) * 2 + 1];
            float wg0 = wg[(c * 16 + ic) * 2 + 0];
            float wg1 = wg[(c * 16 + ic) * 2 + 1];
            fa[c].x = fmaf(wf0, hp[ic].x, fa[c].x);
            fa[c].x = fmaf(wf1, hc[ic].x, fa[c].x);
            fa[c].y = fmaf(wf0, hp[ic].y, fa[c].y);
            fa[c].y = fmaf(wf1, hc[ic].y, fa[c].y);
            ga[c].x = fmaf(wg0, hp[ic].x, ga[c].x);
            ga[c].x = fmaf(wg1, hc[ic].x, ga[c].x);
            ga[c].y = fmaf(wg0, hp[ic].y, ga[c].y);
            ga[c].y = fmaf(wg1, hc[ic].y, ga[c].y);
        }
    }

#pragma unroll
    for (int c = 0; c < 16; ++c) {
        float2 o;
        o.x = fmaf(fast_tanh(fa[c].x), fast_sigmoid(ga[c].x), hc[c].x);
        o.y = fmaf(fast_tanh(fa[c].y), fast_sigmoid(ga[c].y), hc[c].y);
        *(float2*)(hOut + (size_t)c * TOTAL + t0) = o;
    }

#pragma unroll
    for (int sch = 0; sch < 32; ++sch) {
        float2 acc;
        acc.x = acc.y = bskv[sch];
#pragma unroll
        for (int ic = 0; ic < 16; ++ic) {
            float wv = wsk[sch * 16 + ic];
            acc.x = fmaf(wv, hc[ic].x, acc.x);
            acc.y = fmaf(wv, hc[ic].y, acc.y);
        }
        float* sp = skip + (size_t)sch * TOTAL + t0;
        if (firstLayer) {
            *(float2*)sp = acc;
        } else {
            float2 old = *(const float2*)sp;
            acc.x += old.x; acc.y += old.y;
            *(float2*)sp = acc;
        }
    }
}

__global__ __launch_bounds__(256, 2) void final_kernel(
    const float* __restrict__ skip,
    const float* __restrict__ Wagg, const float* __restrict__ bagg,
    const float* __restrict__ Wout, const float* __restrict__ bout,
    float* __restrict__ out)
{
    __shared__ unsigned short agg_bu[64 * 64];
    __shared__ float red_m[64][5];
    __shared__ float red_s[64][5];

    int tid  = threadIdx.x;
    int lane = tid & 63;
    int w    = tid >> 6;
    int posG = blockIdx.x * 64;
    int b    = posG >> LOG2N;
    int nb   = posG & (NPOS - 1);

    {
        int pos = posG + lane;
        float sv[32];
#pragma unroll
        for (int sch = 0; sch < 32; ++sch)
            sv[sch] = fmaxf(skip[(size_t)sch * TOTAL + pos], 0.f);

        float r16[16];
#pragma unroll
        for (int a = 0; a < 16; ++a) {
            int ac = w * 16 + a;
            float acc = bagg[ac];
#pragma unroll
            for (int sch = 0; sch < 32; ++sch)
                acc = fmaf(Wagg[ac * 32 + sch], sv[sch], acc);
            r16[a] = fmaxf(acc, 0.f);
        }
#pragma unroll
        for (int q = 0; q < 8; ++q) {
            unsigned pk = (unsigned)bf16rne(r16[2 * q]) |
                          ((unsigned)bf16rne(r16[2 * q + 1]) << 16);
            int icbyte = (w * 16 + 2 * q) * 2;
            int addr   = lane * 128 + (icbyte ^ ((lane & 7) << 4));
            *(unsigned*)(&agg_bu[addr >> 1]) = pk;
        }
    }
    __syncthreads();

    int lr = lane & 15;
    int lg = lane >> 4;
    int c0 = w * 64;
    short8v afr[4][2];
#pragma unroll
    for (int ct = 0; ct < 4; ++ct) {
#pragma unroll
        for (int kf = 0; kf < 2; ++kf) {
            int cls = c0 + ct * 16 + lr;
            int k0  = kf * 32 + lg * 8;
            const float4* wp = (const float4*)(Wout + (size_t)cls * 64 + k0);
            float4 w0 = wp[0], w1 = wp[1];
            short8v af;
            af[0] = (short)bf16rne(w0.x); af[1] = (short)bf16rne(w0.y);
            af[2] = (short)bf16rne(w0.z); af[3] = (short)bf16rne(w0.w);
            af[4] = (short)bf16rne(w1.x); af[5] = (short)bf16rne(w1.y);
            af[6] = (short)bf16rne(w1.z); af[7] = (short)bf16rne(w1.w);
            afr[ct][kf] = af;
        }
    }

    f32x4 acc[4][4];
#pragma unroll
    for (int pt = 0; pt < 4; ++pt) {
        int pos = pt * 16 + lr;
        int sw  = (pos & 7) << 4;
        const short8v* bp0 = (const short8v*)(&agg_bu[(pos * 128 + ((0 * 64 + lg * 16) ^ sw)) >> 1]);
        const short8v* bp1 = (const short8v*)(&agg_bu[(pos * 128 + ((1 * 64 + lg * 16) ^ sw)) >> 1]);
        short8v bf0 = *bp0;
        short8v bf1 = *bp1;
#pragma unroll
        for (int ct = 0; ct < 4; ++ct) {
            f32x4 c;
#pragma unroll
            for (int r = 0; r < 4; ++r) c[r] = bout[c0 + ct * 16 + lg * 4 + r];
            c = __builtin_amdgcn_mfma_f32_16x16x32_bf16(afr[ct][0], bf0, c, 0, 0, 0);
            c = __builtin_amdgcn_mfma_f32_16x16x32_bf16(afr[ct][1], bf1, c, 0, 0, 0);
            acc[pt][ct] = c;
        }
    }

#pragma unroll
    for (int pt = 0; pt < 4; ++pt) {
        float m = -1e30f;
#pragma unroll
        for (int ct = 0; ct < 4; ++ct)
#pragma unroll
            for (int r = 0; r < 4; ++r) m = fmaxf(m, acc[pt][ct][r]);
        m = fmaxf(m, __shfl_xor(m, 16));
        m = fmaxf(m, __shfl_xor(m, 32));
        float s = 0.f;
#pragma unroll
        for (int ct = 0; ct < 4; ++ct)
#pragma unroll
            for (int r = 0; r < 4; ++r) s += __expf(acc[pt][ct][r] - m);
        s += __shfl_xor(s, 16);
        s += __shfl_xor(s, 32);
        int pos = pt * 16 + lr;
        red_m[pos][w] = m;
        red_s[pos][w] = s;
    }
    __syncthreads();

#pragma unroll
    for (int pt = 0; pt < 4; ++pt) {
        int pos = pt * 16 + lr;
        float M = fmaxf(fmaxf(red_m[pos][0], red_m[pos][1]),
                        fmaxf(red_m[pos][2], red_m[pos][3]));
        float S = 0.f;
#pragma unroll
        for (int k = 0; k < 4; ++k) S += red_s[pos][k] * __expf(red_m[pos][k] - M);
        float logZ = M + __logf(S);

        int n = nb + pos;
#pragma unroll
        for (int ct = 0; ct < 4; ++ct) {
#pragma unroll
            for (int r = 0; r < 4; ++r) {
                int cls = c0 + ct * 16 + lg * 4 + r;
                out[((size_t)(b * 256 + cls)) * NPOS + n] = acc[pt][ct][r] - logZ;
            }
        }
    }
}

extern "C" void kernel_launch(void* const* d_in, const int* in_sizes, int n_in,
                              void* d_out, int out_size, void* d_ws, size_t ws_size,
                              hipStream_t stream)
{
    const int*   x_int = (const int*)  d_in[0];
    const float* W0    = (const float*)d_in[1];
    const float* b0    = (const float*)d_in[2];
    const float* Wf    = (const float*)d_in[3];
    const float* bfv   = (const float*)d_in[4];
    const float* Wg    = (const float*)d_in[5];
    const float* bgv   = (const float*)d_in[6];
    const float* Wsk   = (const float*)d_in[7];
    const float* bskv  = (const float*)d_in[8];
    const float* Wagg  = (const float*)d_in[9];
    const float* bagg  = (const float*)d_in[10];
    const float* Wout  = (const float*)d_in[11];
    const float* bout  = (const float*)d_in[12];
    float* out = (float*)d_out;

    const size_t needDefer = 19 * HBFE * sizeof(unsigned short)   // 152 MiB bf16 H
                           + 2 * HE * sizeof(float);              // 32 MiB fp32 ping-pong

    if (ws_size >= needDefer) {
        // ---------- channel-split defer-skip path ----------
        unsigned short* Hbf = (unsigned short*)d_ws;
        float* hA = (float*)((char*)d_ws + 19 * HBFE * sizeof(unsigned short));
        float* hB = hA + HE;

        init_kernel_rm1<<<TOTAL / 256, 256, 0, stream>>>(x_int, W0, b0, hA, Hbf);

        float* hin = hA;
        float* hout = hB;
        for (int i = 0; i < 18; ++i) {   // layer 18's h-update is dead code
            int d = 1 << ((i + 1) % 10);
            layer_kernel_cs<<<TOTAL / 128, 256, 0, stream>>>(
                hin, hout, Hbf + (size_t)(i + 1) * HBFE,
                Wf + (size_t)i * 512, bfv + (size_t)i * 16,
                Wg + (size_t)i * 512, bgv + (size_t)i * 16, d);
            float* tmp = hin; hin = hout; hout = tmp;
        }
        final_kernel_ds4<<<TOTAL / 64, 256, 0, stream>>>(
            Hbf, Wsk, bskv, Wagg, bagg, Wout, bout, out);
    } else {
        // ---------- R8 fallback (channel-major) ----------
        const int grid2 = TOTAL / (256 * 2);
        const size_t skE = (size_t)32 * TOTAL;
        float* skipb = (float*)d_ws;
        float *hA, *hB;
        if (ws_size >= (skE + 2 * HE) * sizeof(float)) {
            hA = skipb + skE;
            hB = hA + HE;
        } else {
            hA = out + ((size_t)out_size - 2 * HE);
            hB = hA + HE;
        }

        init_kernel2<<<grid2, 256, 0, stream>>>(x_int, W0, b0, hA);
        float* hin = hA;
        float* hout = hB;
        for (int i = 0; i < 19; ++i) {
            int d = 1 << ((i + 1) % 10);
            layer_kernel2<<<grid2, 256, 0, stream>>>(
                hin, hout, skipb,
                Wf + (size_t)i * 512, bfv + (size_t)i * 16,
                Wg + (size_t)i * 512, bgv + (size_t)i * 16,
                Wsk + (size_t)i * 512, bskv + (size_t)i * 32,
                d, (i == 0) ? 1 : 0);
            float* tmp = hin; hin = hout; hout = tmp;
        }
        final_kernel<<<TOTAL / 64, 256, 0, stream>>>(
            skipb, Wagg, bagg, Wout, bout, out);
    }
}

// Round 15
// 676.104 us; speedup vs baseline: 2.8585x; 1.5854x over previous
//
#include <hip/hip_runtime.h>
#include <math.h>
#include <stdint.h>

#define NPOS  32768
#define LOG2N 15
#define BATCH 8
#define TOTAL (BATCH * NPOS)          // 262144 positions
#define HE    ((size_t)16 * TOTAL)    // one fp32 h buffer, elements (16 MiB)

typedef __attribute__((ext_vector_type(8))) short short8v;  // 8 bf16 = 4 VGPR
typedef __attribute__((ext_vector_type(4))) float f32x4;    // MFMA C/D

__device__ __forceinline__ float fast_tanh(float x) {
    float t = __expf(-2.f * x);
    return fmaf(2.f, __builtin_amdgcn_rcpf(1.f + t), -1.f);
}
__device__ __forceinline__ float fast_sigmoid(float x) {
    return __builtin_amdgcn_rcpf(1.f + __expf(-x));
}
__device__ __forceinline__ unsigned short bf16rne(float x) {
    unsigned u = __float_as_uint(x);
    u = (u + 0x7fffu + ((u >> 16) & 1u)) >> 16;
    return (unsigned short)u;
}

// ======================================================================
// Defer-skip path. H_i = [16][TOTAL] fp32 ch-major (19 buffers in ws).
// ======================================================================

// ---- init (ch-major, PPT=2) — R10 verbatim
__global__ __launch_bounds__(256) void init_kernel2(
    const int* __restrict__ x_int, const float* __restrict__ W0,
    const float* __restrict__ b0, float* __restrict__ h)
{
    int t0 = (blockIdx.x * 256 + threadIdx.x) * 2;
    int n0 = t0 & (NPOS - 1);
    const float sc = 1.f / 32768.f;
    float xs0  = (n0 >= 1) ? (float)x_int[t0 - 1] * sc : 0.f;
    float xs1  = (float)x_int[t0] * sc;
    float xsp0 = (n0 >= 2) ? (float)x_int[t0 - 2] * sc : 0.f;
    float xsp1 = xs0;
#pragma unroll
    for (int c = 0; c < 16; ++c) {
        float2 o;
        o.x = xs0 + W0[c * 2 + 0] * xsp0 + W0[c * 2 + 1] * xs0 + b0[c];
        o.y = xs1 + W0[c * 2 + 0] * xsp1 + W0[c * 2 + 1] * xs1 + b0[c];
        *(float2*)(h + (size_t)c * TOTAL + t0) = o;
    }
}

// ---- residual layer, d=512 only — R10's layer_kernel_ns verbatim
__global__ __launch_bounds__(256, 2) void layer_kernel_ns(
    const float* __restrict__ hIn, float* __restrict__ hOut,
    const float* __restrict__ wf, const float* __restrict__ bfv,
    const float* __restrict__ wg, const float* __restrict__ bgv,
    int d)
{
    int t0 = (blockIdx.x * 256 + threadIdx.x) * 2;
    int n0 = t0 & (NPOS - 1);

    float2 hc[16], hp[16];
#pragma unroll
    for (int ic = 0; ic < 16; ++ic)
        hc[ic] = *(const float2*)(hIn + (size_t)ic * TOTAL + t0);

    {
        bool v = (n0 >= d);
        int tm = v ? (t0 - d) : t0;
#pragma unroll
        for (int ic = 0; ic < 16; ++ic) {
            float2 x = *(const float2*)(hIn + (size_t)ic * TOTAL + tm);
            hp[ic].x = v ? x.x : 0.f;
            hp[ic].y = v ? x.y : 0.f;
        }
    }

    float2 fa[16], ga[16];
#pragma unroll
    for (int c = 0; c < 16; ++c) {
        fa[c].x = fa[c].y = bfv[c];
        ga[c].x = ga[c].y = bgv[c];
    }
#pragma unroll
    for (int c = 0; c < 16; ++c) {
#pragma unroll
        for (int ic = 0; ic < 16; ++ic) {
            float wf0 = wf[(c * 16 + ic) * 2 + 0];
            float wf1 = wf[(c * 16 + ic) * 2 + 1];
            float wg0 = wg[(c * 16 + ic) * 2 + 0];
            float wg1 = wg[(c * 16 + ic) * 2 + 1];
            fa[c].x = fmaf(wf0, hp[ic].x, fa[c].x);
            fa[c].x = fmaf(wf1, hc[ic].x, fa[c].x);
            fa[c].y = fmaf(wf0, hp[ic].y, fa[c].y);
            fa[c].y = fmaf(wf1, hc[ic].y, fa[c].y);
            ga[c].x = fmaf(wg0, hp[ic].x, ga[c].x);
            ga[c].x = fmaf(wg1, hc[ic].x, ga[c].x);
            ga[c].y = fmaf(wg0, hp[ic].y, ga[c].y);
            ga[c].y = fmaf(wg1, hc[ic].y, ga[c].y);
        }
    }

#pragma unroll
    for (int c = 0; c < 16; ++c) {
        float2 o;
        o.x = fmaf(fast_tanh(fa[c].x), fast_sigmoid(ga[c].x), hc[c].x);
        o.y = fmaf(fast_tanh(fa[c].y), fast_sigmoid(ga[c].y), hc[c].y);
        *(float2*)(hOut + (size_t)c * TOTAL + t0) = o;
    }
}

// ---- residual layer with LDS halo sharing (d <= 256) ----------------------
// Block covers 512 positions. Phase 1: cooperatively stage hc rows + d-row
// halo into LDS (bytes: (512+d)/512 x 16MB instead of 32MB). Phase 2: R10's
// exact compute core reading hc/hp from LDS. fp32 pass-through: bit-identical.
__global__ __launch_bounds__(256, 2) void layer_kernel_lds(
    const float* __restrict__ hIn, float* __restrict__ hOut,
    const float* __restrict__ wf, const float* __restrict__ bfv,
    const float* __restrict__ wg, const float* __restrict__ bgv,
    int ld)                                    // d = 1 << ld, ld <= 8
{
    __shared__ float hsh[16 * 768];            // stride S = 512 + dpad (<=768)

    int d    = 1 << ld;
    int dpad = (d < 4) ? 4 : d;
    int S    = 512 + dpad;
    int base = blockIdx.x * 512;

    // phase 1a: main rows [base, base+512), 8x float4 per thread, coalesced
    {
        int q = threadIdx.x;
#pragma unroll
        for (int r = 0; r < 8; ++r, q += 256) {
            int ic = q >> 7;                   // 128 float4 per channel
            int w4 = q & 127;
            float4 v = *(const float4*)(hIn + (size_t)ic * TOTAL + base + w4 * 4);
            *(float4*)(&hsh[ic * S + dpad + w4 * 4]) = v;
        }
    }
    // phase 1b: halo rows [base-d, base), scalar (d*16 floats total)
    for (int idx = threadIdx.x; idx < (16 << ld); idx += 256) {
        int ic = idx >> ld;
        int j  = idx & (d - 1);
        int t  = base - d + j;
        int tc = (t < 0) ? 0 : t;
        hsh[ic * S + (dpad - d) + j] = hIn[(size_t)ic * TOTAL + tc];
    }
    __syncthreads();

    // phase 2: R10 compute core, hc/hp from LDS
    int t0 = base + threadIdx.x * 2;
    int n0 = t0 & (NPOS - 1);
    int jj = dpad + threadIdx.x * 2;

    float2 hc[16], hp[16];
#pragma unroll
    for (int ic = 0; ic < 16; ++ic)
        hc[ic] = *(const float2*)(&hsh[ic * S + jj]);

    if (d == 1) {
        bool v = (n0 >= 1);
#pragma unroll
        for (int ic = 0; ic < 16; ++ic) {
            float x = hsh[ic * S + jj - 1];
            hp[ic].x = v ? x : 0.f;
            hp[ic].y = hc[ic].x;
        }
    } else {
        bool v = (n0 >= d);
#pragma unroll
        for (int ic = 0; ic < 16; ++ic) {
            float2 x = *(const float2*)(&hsh[ic * S + jj - d]);
            hp[ic].x = v ? x.x : 0.f;
            hp[ic].y = v ? x.y : 0.f;
        }
    }

    float2 fa[16], ga[16];
#pragma unroll
    for (int c = 0; c < 16; ++c) {
        fa[c].x = fa[c].y = bfv[c];
        ga[c].x = ga[c].y = bgv[c];
    }
#pragma unroll
    for (int c = 0; c < 16; ++c) {
#pragma unroll
        for (int ic = 0; ic < 16; ++ic) {
            float wf0 = wf[(c * 16 + ic) * 2 + 0];
            float wf1 = wf[(c * 16 + ic) * 2 + 1];
            float wg0 = wg[(c * 16 + ic) * 2 + 0];
            float wg1 = wg[(c * 16 + ic) * 2 + 1];
            fa[c].x = fmaf(wf0, hp[ic].x, fa[c].x);
            fa[c].x = fmaf(wf1, hc[ic].x, fa[c].x);
            fa[c].y = fmaf(wf0, hp[ic].y, fa[c].y);
            fa[c].y = fmaf(wf1, hc[ic].y, fa[c].y);
            ga[c].x = fmaf(wg0, hp[ic].x, ga[c].x);
            ga[c].x = fmaf(wg1, hc[ic].x, ga[c].x);
            ga[c].y = fmaf(wg0, hp[ic].y, ga[c].y);
            ga[c].y = fmaf(wg1, hc[ic].y, ga[c].y);
        }
    }

#pragma unroll
    for (int c = 0; c < 16; ++c) {
        float2 o;
        o.x = fmaf(fast_tanh(fa[c].x), fast_sigmoid(ga[c].x), hc[c].x);
        o.y = fmaf(fast_tanh(fa[c].y), fast_sigmoid(ga[c].y), hc[c].y);
        *(float2*)(hOut + (size_t)c * TOTAL + t0) = o;
    }
}

// ---- final: MFMA skip-sum (fp32 ch-major H) + agg + MFMA logits -----------
// R10's final_kernel_ds2 verbatim (validated, 250 us)
__global__ __launch_bounds__(256, 2) void final_kernel_ds2(
    const float* __restrict__ Hbase,
    const float* __restrict__ Wsk,  const float* __restrict__ bskv,
    const float* __restrict__ Wagg, const float* __restrict__ bagg,
    const float* __restrict__ Wout, const float* __restrict__ bout,
    float* __restrict__ out)
{
    __shared__ float sv_lds[64][33];
    __shared__ unsigned short agg_bu[64 * 64];
    __shared__ float red_m[64][5];
    __shared__ float red_s[64][5];
    __shared__ float bsum[32];

    int tid  = threadIdx.x;
    int lane = tid & 63;
    int w    = tid >> 6;
    int posG = blockIdx.x * 64;
    int b    = posG >> LOG2N;
    int nb   = posG & (NPOS - 1);

    int lr = lane & 15;
    int lg = lane >> 4;

    if (tid < 32) {
        float s = 0.f;
#pragma unroll 1
        for (int i = 0; i < 19; ++i) s += bskv[i * 32 + tid];
        bsum[tid] = s;
    }

    int posGlob = posG + w * 16 + lr;

    f32x4 dsk0 = {0.f, 0.f, 0.f, 0.f};
    f32x4 dsk1 = {0.f, 0.f, 0.f, 0.f};

#pragma unroll
    for (int kt = 0; kt < 10; ++kt) {
        int i   = kt * 2 + (lg >> 1);
        int ic0 = (lg & 1) * 8;
        short8v bfr = {0, 0, 0, 0, 0, 0, 0, 0};
        short8v af0 = {0, 0, 0, 0, 0, 0, 0, 0};
        short8v af1 = {0, 0, 0, 0, 0, 0, 0, 0};
        if (i < 19) {
            const float* hb = Hbase + (size_t)i * HE + (size_t)ic0 * TOTAL + posGlob;
#pragma unroll
            for (int j = 0; j < 8; ++j)
                bfr[j] = (short)bf16rne(hb[(size_t)j * TOTAL]);

            const float4* wp0 = (const float4*)(Wsk + (size_t)i * 512 + (0 * 16 + lr) * 16 + ic0);
            const float4* wp1 = (const float4*)(Wsk + (size_t)i * 512 + (1 * 16 + lr) * 16 + ic0);
            float4 a0 = wp0[0], a1 = wp0[1];
            float4 c0v = wp1[0], c1v = wp1[1];
            af0[0] = (short)bf16rne(a0.x); af0[1] = (short)bf16rne(a0.y);
            af0[2] = (short)bf16rne(a0.z); af0[3] = (short)bf16rne(a0.w);
            af0[4] = (short)bf16rne(a1.x); af0[5] = (short)bf16rne(a1.y);
            af0[6] = (short)bf16rne(a1.z); af0[7] = (short)bf16rne(a1.w);
            af1[0] = (short)bf16rne(c0v.x); af1[1] = (short)bf16rne(c0v.y);
            af1[2] = (short)bf16rne(c0v.z); af1[3] = (short)bf16rne(c0v.w);
            af1[4] = (short)bf16rne(c1v.x); af1[5] = (short)bf16rne(c1v.y);
            af1[6] = (short)bf16rne(c1v.z); af1[7] = (short)bf16rne(c1v.w);
        }
        dsk0 = __builtin_amdgcn_mfma_f32_16x16x32_bf16(af0, bfr, dsk0, 0, 0, 0);
        dsk1 = __builtin_amdgcn_mfma_f32_16x16x32_bf16(af1, bfr, dsk1, 0, 0, 0);
    }

    __syncthreads();

    {
        int posL = w * 16 + lr;
#pragma unroll
        for (int r = 0; r < 4; ++r) {
            int sc0 = 0 * 16 + lg * 4 + r;
            int sc1 = 1 * 16 + lg * 4 + r;
            sv_lds[posL][sc0] = fmaxf(dsk0[r] + bsum[sc0], 0.f);
            sv_lds[posL][sc1] = fmaxf(dsk1[r] + bsum[sc1], 0.f);
        }
    }
    __syncthreads();

    {
        float sv[32];
#pragma unroll
        for (int sch = 0; sch < 32; ++sch) sv[sch] = sv_lds[lane][sch];

        float r16[16];
#pragma unroll
        for (int a = 0; a < 16; ++a) {
            int ac = w * 16 + a;
            float acc = bagg[ac];
#pragma unroll
            for (int sch = 0; sch < 32; ++sch)
                acc = fmaf(Wagg[ac * 32 + sch], sv[sch], acc);
            r16[a] = fmaxf(acc, 0.f);
        }
#pragma unroll
        for (int q = 0; q < 8; ++q) {
            unsigned pk = (unsigned)bf16rne(r16[2 * q]) |
                          ((unsigned)bf16rne(r16[2 * q + 1]) << 16);
            int icbyte = (w * 16 + 2 * q) * 2;
            int addr   = lane * 128 + (icbyte ^ ((lane & 7) << 4));
            *(unsigned*)(&agg_bu[addr >> 1]) = pk;
        }
    }
    __syncthreads();

    int c0 = w * 64;
    short8v afr[4][2];
#pragma unroll
    for (int ct = 0; ct < 4; ++ct) {
#pragma unroll
        for (int kf = 0; kf < 2; ++kf) {
            int cls = c0 + ct * 16 + lr;
            int k0  = kf * 32 + lg * 8;
            const float4* wp = (const float4*)(Wout + (size_t)cls * 64 + k0);
            float4 w0 = wp[0], w1 = wp[1];
            short8v af;
            af[0] = (short)bf16rne(w0.x); af[1] = (short)bf16rne(w0.y);
            af[2] = (short)bf16rne(w0.z); af[3] = (short)bf16rne(w0.w);
            af[4] = (short)bf16rne(w1.x); af[5] = (short)bf16rne(w1.y);
            af[6] = (short)bf16rne(w1.z); af[7] = (short)bf16rne(w1.w);
            afr[ct][kf] = af;
        }
    }

    f32x4 acc[4][4];
#pragma unroll
    for (int pt = 0; pt < 4; ++pt) {
        int pos = pt * 16 + lr;
        int sw  = (pos & 7) << 4;
        const short8v* bp0 = (const short8v*)(&agg_bu[(pos * 128 + ((0 * 64 + lg * 16) ^ sw)) >> 1]);
        const short8v* bp1 = (const short8v*)(&agg_bu[(pos * 128 + ((1 * 64 + lg * 16) ^ sw)) >> 1]);
        short8v bf0 = *bp0;
        short8v bf1 = *bp1;
#pragma unroll
        for (int ct = 0; ct < 4; ++ct) {
            f32x4 c;
#pragma unroll
            for (int r = 0; r < 4; ++r) c[r] = bout[c0 + ct * 16 + lg * 4 + r];
            c = __builtin_amdgcn_mfma_f32_16x16x32_bf16(afr[ct][0], bf0, c, 0, 0, 0);
            c = __builtin_amdgcn_mfma_f32_16x16x32_bf16(afr[ct][1], bf1, c, 0, 0, 0);
            acc[pt][ct] = c;
        }
    }

#pragma unroll
    for (int pt = 0; pt < 4; ++pt) {
        float m = -1e30f;
#pragma unroll
        for (int ct = 0; ct < 4; ++ct)
#pragma unroll
            for (int r = 0; r < 4; ++r) m = fmaxf(m, acc[pt][ct][r]);
        m = fmaxf(m, __shfl_xor(m, 16));
        m = fmaxf(m, __shfl_xor(m, 32));
        float s = 0.f;
#pragma unroll
        for (int ct = 0; ct < 4; ++ct)
#pragma unroll
            for (int r = 0; r < 4; ++r) s += __expf(acc[pt][ct][r] - m);
        s += __shfl_xor(s, 16);
        s += __shfl_xor(s, 32);
        int pos = pt * 16 + lr;
        red_m[pos][w] = m;
        red_s[pos][w] = s;
    }
    __syncthreads();

#pragma unroll
    for (int pt = 0; pt < 4; ++pt) {
        int pos = pt * 16 + lr;
        float M = fmaxf(fmaxf(red_m[pos][0], red_m[pos][1]),
                        fmaxf(red_m[pos][2], red_m[pos][3]));
        float S = 0.f;
#pragma unroll
        for (int k = 0; k < 4; ++k) S += red_s[pos][k] * __expf(red_m[pos][k] - M);
        float logZ = M + __logf(S);

        int n = nb + pos;
#pragma unroll
        for (int ct = 0; ct < 4; ++ct) {
#pragma unroll
            for (int r = 0; r < 4; ++r) {
                int cls = c0 + ct * 16 + lg * 4 + r;
                out[((size_t)(b * 256 + cls)) * NPOS + n] = acc[pt][ct][r] - logZ;
            }
        }
    }
}

// ======================================================================
// R8 fallback path (channel-major, skip-RMW) — kept verbatim
// ======================================================================
__global__ __launch_bounds__(256, 2) void layer_kernel2(
    const float* __restrict__ hIn, float* __restrict__ hOut,
    float* __restrict__ skip,
    const float* __restrict__ wf, const float* __restrict__ bfv,
    const float* __restrict__ wg, const float* __restrict__ bgv,
    const float* __restrict__ wsk, const float* __restrict__ bskv,
    int d, int firstLayer)
{
    int t0 = (blockIdx.x * 256 + threadIdx.x) * 2;
    int n0 = t0 & (NPOS - 1);

    float2 hc[16], hp[16];
#pragma unroll
    for (int ic = 0; ic < 16; ++ic)
        hc[ic] = *(const float2*)(hIn + (size_t)ic * TOTAL + t0);

    if (d == 1) {
        bool v = (n0 >= 1);
        int tm = v ? (t0 - 1) : t0;
#pragma unroll
        for (int ic = 0; ic < 16; ++ic) {
            float x = hIn[(size_t)ic * TOTAL + tm];
            hp[ic].x = v ? x : 0.f;
            hp[ic].y = hc[ic].x;
        }
    } else {
        bool v = (n0 >= d);
        int tm = v ? (t0 - d) : t0;
#pragma unroll
        for (int ic = 0; ic < 16; ++ic) {
            float2 x = *(const float2*)(hIn + (size_t)ic * TOTAL + tm);
            hp[ic].x = v ? x.x : 0.f;
            hp[ic].y = v ? x.y : 0.f;
        }
    }

    float2 fa[16], ga[16];
#pragma unroll
    for (int c = 0; c < 16; ++c) {
        fa[c].x = fa[c].y = bfv[c];
        ga[c].x = ga[c].y = bgv[c];
    }
#pragma unroll
    for (int c = 0; c < 16; ++c) {
#pragma unroll
        for (int ic = 0; ic < 16; ++ic) {
            float wf0 = wf[(c * 16 + ic) * 2 + 0];
            float wf1 = wf[(c * 16 + ic) * 2 + 1];
            float wg0 = wg[(c * 16 + ic) * 2 + 0];
            float wg1 = wg[(c * 16 + ic) * 2 + 1];
            fa[c].x = fmaf(wf0, hp[ic].x, fa[c].x);
            fa[c].x = fmaf(wf1, hc[ic].x, fa[c].x);
            fa[c].y = fmaf(wf0, hp[ic].y, fa[c].y);
            fa[c].y = fmaf(wf1, hc[ic].y, fa[c].y);
            ga[c].x = fmaf(wg0, hp[ic].x, ga[c].x);
            ga[c].x = fmaf(wg1, hc[ic].x, ga[c].x);
            ga[c].y = fmaf(wg0, hp[ic].y, ga[c].y);
            ga[c].y = fmaf(wg1, hc[ic].y, ga[c].y);
        }
    }

#pragma unroll
    for (int c = 0; c < 16; ++c) {
        float2 o;
        o.x = fmaf(fast_tanh(fa[c].x), fast_sigmoid(ga[c].x), hc[c].x);
        o.y = fmaf(fast_tanh(fa[c].y), fast_sigmoid(ga[c].y), hc[c].y);
        *(float2*)(hOut + (size_t)c * TOTAL + t0) = o;
    }

#pragma unroll
    for (int sch = 0; sch < 32; ++sch) {
        float2 acc;
        acc.x = acc.y = bskv[sch];
#pragma unroll
        for (int ic = 0; ic < 16; ++ic) {
            float wv = wsk[sch * 16 + ic];
            acc.x = fmaf(wv, hc[ic].x, acc.x);
            acc.y = fmaf(wv, hc[ic].y, acc.y);
        }
        float* sp = skip + (size_t)sch * TOTAL + t0;
        if (firstLayer) {
            *(float2*)sp = acc;
        } else {
            float2 old = *(const float2*)sp;
            acc.x += old.x; acc.y += old.y;
            *(float2*)sp = acc;
        }
    }
}

__global__ __launch_bounds__(256, 2) void final_kernel(
    const float* __restrict__ skip,
    const float* __restrict__ Wagg, const float* __restrict__ bagg,
    const float* __restrict__ Wout, const float* __restrict__ bout,
    float* __restrict__ out)
{
    __shared__ unsigned short agg_bu[64 * 64];
    __shared__ float red_m[64][5];
    __shared__ float red_s[64][5];

    int tid  = threadIdx.x;
    int lane = tid & 63;
    int w    = tid >> 6;
    int posG = blockIdx.x * 64;
    int b    = posG >> LOG2N;
    int nb   = posG & (NPOS - 1);

    {
        int pos = posG + lane;
        float sv[32];
#pragma unroll
        for (int sch = 0; sch < 32; ++sch)
            sv[sch] = fmaxf(skip[(size_t)sch * TOTAL + pos], 0.f);

        float r16[16];
#pragma unroll
        for (int a = 0; a < 16; ++a) {
            int ac = w * 16 + a;
            float acc = bagg[ac];
#pragma unroll
            for (int sch = 0; sch < 32; ++sch)
                acc = fmaf(Wagg[ac * 32 + sch], sv[sch], acc);
            r16[a] = fmaxf(acc, 0.f);
        }
#pragma unroll
        for (int q = 0; q < 8; ++q) {
            unsigned pk = (unsigned)bf16rne(r16[2 * q]) |
                          ((unsigned)bf16rne(r16[2 * q + 1]) << 16);
            int icbyte = (w * 16 + 2 * q) * 2;
            int addr   = lane * 128 + (icbyte ^ ((lane & 7) << 4));
            *(unsigned*)(&agg_bu[addr >> 1]) = pk;
        }
    }
    __syncthreads();

    int lr = lane & 15;
    int lg = lane >> 4;
    int c0 = w * 64;
    short8v afr[4][2];
#pragma unroll
    for (int ct = 0; ct < 4; ++ct) {
#pragma unroll
        for (int kf = 0; kf < 2; ++kf) {
            int cls = c0 + ct * 16 + lr;
            int k0  = kf * 32 + lg * 8;
            const float4* wp = (const float4*)(Wout + (size_t)cls * 64 + k0);
            float4 w0 = wp[0], w1 = wp[1];
            short8v af;
            af[0] = (short)bf16rne(w0.x); af[1] = (short)bf16rne(w0.y);
            af[2] = (short)bf16rne(w0.z); af[3] = (short)bf16rne(w0.w);
            af[4] = (short)bf16rne(w1.x); af[5] = (short)bf16rne(w1.y);
            af[6] = (short)bf16rne(w1.z); af[7] = (short)bf16rne(w1.w);
            afr[ct][kf] = af;
        }
    }

    f32x4 acc[4][4];
#pragma unroll
    for (int pt = 0; pt < 4; ++pt) {
        int pos = pt * 16 + lr;
        int sw  = (pos & 7) << 4;
        const short8v* bp0 = (const short8v*)(&agg_bu[(pos * 128 + ((0 * 64 + lg * 16) ^ sw)) >> 1]);
        const short8v* bp1 = (const short8v*)(&agg_bu[(pos * 128 + ((1 * 64 + lg * 16) ^ sw)) >> 1]);
        short8v bf0 = *bp0;
        short8v bf1 = *bp1;
#pragma unroll
        for (int ct = 0; ct < 4; ++ct) {
            f32x4 c;
#pragma unroll
            for (int r = 0; r < 4; ++r) c[r] = bout[c0 + ct * 16 + lg * 4 + r];
            c = __builtin_amdgcn_mfma_f32_16x16x32_bf16(afr[ct][0], bf0, c, 0, 0, 0);
            c = __builtin_amdgcn_mfma_f32_16x16x32_bf16(afr[ct][1], bf1, c, 0, 0, 0);
            acc[pt][ct] = c;
        }
    }

#pragma unroll
    for (int pt = 0; pt < 4; ++pt) {
        float m = -1e30f;
#pragma unroll
        for (int ct = 0; ct < 4; ++ct)
#pragma unroll
            for (int r = 0; r < 4; ++r) m = fmaxf(m, acc[pt][ct][r]);
        m = fmaxf(m, __shfl_xor(m, 16));
        m = fmaxf(m, __shfl_xor(m, 32));
        float s = 0.f;
#pragma unroll
        for (int ct = 0; ct < 4; ++ct)
#pragma unroll
            for (int r = 0; r < 4; ++r) s += __expf(acc[pt][ct][r] - m);
        s += __shfl_xor(s, 16);
        s += __shfl_xor(s, 32);
        int pos = pt * 16 + lr;
        red_m[pos][w] = m;
        red_s[pos][w] = s;
    }
    __syncthreads();

#pragma unroll
    for (int pt = 0; pt < 4; ++pt) {
        int pos = pt * 16 + lr;
        float M = fmaxf(fmaxf(red_m[pos][0], red_m[pos][1]),
                        fmaxf(red_m[pos][2], red_m[pos][3]));
        float S = 0.f;
#pragma unroll
        for (int k = 0; k < 4; ++k) S += red_s[pos][k] * __expf(red_m[pos][k] - M);
        float logZ = M + __logf(S);

        int n = nb + pos;
#pragma unroll
        for (int ct = 0; ct < 4; ++ct) {
#pragma unroll
            for (int r = 0; r < 4; ++r) {
                int cls = c0 + ct * 16 + lg * 4 + r;
                out[((size_t)(b * 256 + cls)) * NPOS + n] = acc[pt][ct][r] - logZ;
            }
        }
    }
}

extern "C" void kernel_launch(void* const* d_in, const int* in_sizes, int n_in,
                              void* d_out, int out_size, void* d_ws, size_t ws_size,
                              hipStream_t stream)
{
    const int*   x_int = (const int*)  d_in[0];
    const float* W0    = (const float*)d_in[1];
    const float* b0    = (const float*)d_in[2];
    const float* Wf    = (const float*)d_in[3];
    const float* bfv   = (const float*)d_in[4];
    const float* Wg    = (const float*)d_in[5];
    const float* bgv   = (const float*)d_in[6];
    const float* Wsk   = (const float*)d_in[7];
    const float* bskv  = (const float*)d_in[8];
    const float* Wagg  = (const float*)d_in[9];
    const float* bagg  = (const float*)d_in[10];
    const float* Wout  = (const float*)d_in[11];
    const float* bout  = (const float*)d_in[12];
    float* out = (float*)d_out;

    const int grid2 = TOTAL / (256 * 2);   // 512 blocks, 2 pos/thread

    const size_t needDefer = 19 * HE * sizeof(float);   // 304 MiB

    if (ws_size >= needDefer) {
        // ---------- defer-skip path (R10 + LDS halo sharing) ----------
        float* Hb = (float*)d_ws;   // H_i at Hb + i*HE, ch-major [16][TOTAL]

        init_kernel2<<<grid2, 256, 0, stream>>>(x_int, W0, b0, Hb);
        for (int i = 0; i < 18; ++i) {   // layer 18's h-update is dead code
            int ld = (i + 1) % 10;       // d = 1 << ld
            const float* hin = Hb + (size_t)i * HE;
            float* hout = Hb + (size_t)(i + 1) * HE;
            if (ld == 9) {
                layer_kernel_ns<<<grid2, 256, 0, stream>>>(
                    hin, hout,
                    Wf + (size_t)i * 512, bfv + (size_t)i * 16,
                    Wg + (size_t)i * 512, bgv + (size_t)i * 16, 512);
            } else {
                layer_kernel_lds<<<grid2, 256, 0, stream>>>(
                    hin, hout,
                    Wf + (size_t)i * 512, bfv + (size_t)i * 16,
                    Wg + (size_t)i * 512, bgv + (size_t)i * 16, ld);
            }
        }
        final_kernel_ds2<<<TOTAL / 64, 256, 0, stream>>>(
            Hb, Wsk, bskv, Wagg, bagg, Wout, bout, out);
    } else {
        // ---------- R8 fallback (channel-major) ----------
        const size_t skE = (size_t)32 * TOTAL;
        float* skipb = (float*)d_ws;
        float *hA, *hB;
        if (ws_size >= (skE + 2 * HE) * sizeof(float)) {
            hA = skipb + skE;
            hB = hA + HE;
        } else {
            hA = out + ((size_t)out_size - 2 * HE);
            hB = hA + HE;
        }

        init_kernel2<<<grid2, 256, 0, stream>>>(x_int, W0, b0, hA);
        float* hin = hA;
        float* hout = hB;
        for (int i = 0; i < 19; ++i) {
            int d = 1 << ((i + 1) % 10);
            layer_kernel2<<<grid2, 256, 0, stream>>>(
                hin, hout, skipb,
                Wf + (size_t)i * 512, bfv + (size_t)i * 16,
                Wg + (size_t)i * 512, bgv + (size_t)i * 16,
                Wsk + (size_t)i * 512, bskv + (size_t)i * 32,
                d, (i == 0) ? 1 : 0);
            float* tmp = hin; hin = hout; hout = tmp;
        }
        final_kernel<<<TOTAL / 64, 256, 0, stream>>>(
            skipb, Wagg, bagg, Wout, bout, out);
    }
}